// Round 10
// baseline (27.604 us; speedup 1.0000x reference)
//
#include <hip/hip_runtime.h>
#include <math.h>

// Beamline: D(0.45) [Q_c D(0.9)]x19 Q_19 D(0.45). Output = hypot(std(x)-s, std(y)-s).
// Only final x,y matter -> final px,py, z-channel, n_slices all dead.
//   x_f = m11(pz)*x0 + m12(pz)*px0  (chromatic linear map, deg-3 Chebyshev in pz;
//         map is analytic w/ pole at pz=-1 -> Taylor decay (6.5e-3)^k, deg-3
//         truncation ~1e-8 relative, invisible at f32)
//       + cubic(x0,px0,y0,py0)      (first-order drift-nonlinearity kicks, pz=0)
// Round-10: LEAN 2-node fusion. R9's fusion failure mechanism: pre-issued loads
// (20 VGPR) held across f64 prep whose wave-0 path holds con[20] (40 VGPR) ->
// register allocation = max over paths -> occupancy collapse; plus Phase A/B
// serial on wave 0. Fixes: no pre-issue; Phase A = 4 nodes x 32 cells on waves
// 0-1; Phase B on wave 2 (concurrent); launch_bounds(256,4); 1954 blocks x 4
// particles/thread (R8's proven beam config).
// Lessons kept: no contended atomics (R2), no dynamic-index arrays (R3), no
// per-block device-scope fences / lastblock counters (R6).

#define SIGMA_T 0.005
#define PZ_A 6.5e-3
#define NNODE 4
#define MAXQ 32
#define MAXBLK 4096

// cos(pi*(2i+1)/8), i = 0..3
#define U0  0.9238795325112867
#define U1  0.3826834323650898
#define U2 (-0.3826834323650898)
#define U3 (-0.9238795325112867)

struct M2 { double a11, a12, a21, a22; };

// quad 2x2 via signed-u series: u = A*L^2, C=sum u^k/(2k)!, S=sum u^k/(2k+1)!
// cos/cosh and sin/sinh unify; matches Bmad quad_mat2_calc to ~1e-17 for |u|<=0.05.
__device__ inline M2 quadmatS(double A, double rp, double irp, double L) {
    double u = A * L * L;
    double C = fma(u, fma(u, fma(u, fma(u, fma(u, fma(u, 1.0/479001600.0, 1.0/3628800.0),
                    1.0/40320.0), 1.0/720.0), 1.0/24.0), 0.5), 1.0);
    double S = fma(u, fma(u, fma(u, fma(u, fma(u, fma(u, 1.0/6227020800.0, 1.0/39916800.0),
                    1.0/362880.0), 1.0/5040.0), 1.0/120.0), 1.0/6.0), 1.0);
    M2 m;
    double LS = L * S;
    m.a11 = C;
    m.a12 = LS * irp;
    m.a21 = A * LS * rp;
    m.a22 = C;
    return m;
}
__device__ inline void lmul(M2& M, const M2& E) {  // M <- E*M
    double n11 = E.a11*M.a11 + E.a12*M.a21;
    double n12 = E.a11*M.a12 + E.a12*M.a22;
    double n21 = E.a21*M.a11 + E.a22*M.a21;
    double n22 = E.a21*M.a12 + E.a22*M.a22;
    M.a11=n11; M.a12=n12; M.a21=n21; M.a22=n22;
}
__device__ inline void ldrift(M2& M, double d) {   // M <- [[1,d],[0,1]]*M
    M.a11 += d * M.a21;
    M.a12 += d * M.a22;
}
__device__ inline M2 mmul(const M2& A, const M2& B) {  // A*B
    M2 r;
    r.a11 = A.a11*B.a11 + A.a12*B.a21;
    r.a12 = A.a11*B.a12 + A.a12*B.a22;
    r.a21 = A.a21*B.a11 + A.a22*B.a21;
    r.a22 = A.a21*B.a12 + A.a22*B.a22;
    return r;
}
__device__ inline M2 shfl_down_m2(const M2& m, int d, int w) {
    M2 r;
    r.a11 = __shfl_down(m.a11, d, w);
    r.a12 = __shfl_down(m.a12, d, w);
    r.a21 = __shfl_down(m.a21, d, w);
    r.a22 = __shfl_down(m.a22, d, w);
    return r;
}
__device__ inline M2 shfl_up_m2(const M2& m, int d, int w) {
    M2 r;
    r.a11 = __shfl_up(m.a11, d, w);
    r.a12 = __shfl_up(m.a12, d, w);
    r.a21 = __shfl_up(m.a21, d, w);
    r.a22 = __shfl_up(m.a22, d, w);
    return r;
}

__device__ inline float uniflds(const float* p) {
    return __int_as_float(__builtin_amdgcn_readfirstlane(__float_as_int(*p)));
}

// cfs layout (LDS):
//  [0..15]  horner: f*4+k, f in {mx11,mx12,my11,my12}, ascending power of t=pz/PZ_A
//  [16..25] Cx[10]: dx = x(C0 xx+C1 xp+C2 pp+C4 yy+C5 yq+C6 qq) + p(C3 pp+C7 yy+C8 yq+C9 qq)
//  [26..35] Cy[10]: symmetric
__global__ __launch_bounds__(256, 4) void beam_fused_kernel(
    const float* __restrict__ xs, const float* __restrict__ pxs,
    const float* __restrict__ ys, const float* __restrict__ pys,
    const float* __restrict__ pzs, const float* __restrict__ ks,
    int Q, int n4, int ntail, float4* __restrict__ partials)
{
    __shared__ double Mn[NNODE][4];
    __shared__ float  cfs[36];
    __shared__ float  klds[MAXQ];

    const int tid  = threadIdx.x;
    const int lane = tid & 63;
    const int wid  = tid >> 6;
    if (Q > MAXQ) Q = MAXQ;

    if (tid < MAXQ) klds[tid] = (tid < Q) ? ks[tid] : 0.0f;
    __syncthreads();   // klds visible

    if (tid < 128) {
        // ---- Phase A (waves 0-1): 4 Chebyshev nodes x 32 cells, ordered
        //      5-step shuffle tree product (R8 structure, absmax==0 verified)
        const int cell = tid & 31;
        const int node = tid >> 5;
        const double TNv[NNODE] = {U0, U1, U2, U3};
        double t = TNv[node];            // uniform within 32-group
        double pz = PZ_A * t;
        double rp = 1.0 + pz;
        double irp = 1.0 / rp;
        M2 X{1,0,0,1}, Y{1,0,0,1};
        if (cell < Q) {
            if (cell == 0) { ldrift(X, 0.45*irp); ldrift(Y, 0.45*irp); }
            double k1n = (double)klds[cell] * irp;
            lmul(X, quadmatS(-k1n, rp, irp, 0.1));
            lmul(Y, quadmatS( k1n, rp, irp, 0.1));
            double d = ((cell == Q-1) ? 0.45 : 0.9) * irp;
            ldrift(X, d); ldrift(Y, d);
        }
        #pragma unroll
        for (int s = 0; s < 5; ++s) {
            M2 TX = shfl_down_m2(X, 1 << s, 32);
            M2 TY = shfl_down_m2(Y, 1 << s, 32);
            X = mmul(TX, X);
            Y = mmul(TY, Y);
        }
        if (cell == 0) {
            Mn[node][0]=X.a11; Mn[node][1]=X.a12; Mn[node][2]=Y.a11; Mn[node][3]=Y.a12;
        }
    } else if (wid == 2) {
        // ---- Phase B (wave 2, concurrent with A): cubic drift-kick coeffs at
        //      pz=0 via Hillis-Steele prefix matrix scan over drifts (R8) ----
        M2 X{1,0,0,1}, Y{1,0,0,1};
        if (lane >= 1 && lane <= Q) {
            double Lprev = (lane == 1) ? 0.45 : 0.9;
            ldrift(X, Lprev); ldrift(Y, Lprev);
            double k1 = (double)klds[lane-1];
            lmul(X, quadmatS(-k1, 1.0, 1.0, 0.1));
            lmul(Y, quadmatS( k1, 1.0, 1.0, 0.1));
        }
        #pragma unroll
        for (int s = 0; s < 5; ++s) {
            M2 TX = shfl_up_m2(X, 1 << s, 64);
            M2 TY = shfl_up_m2(Y, 1 << s, 64);
            if (lane >= (1 << s)) { X = mmul(X, TX); Y = mmul(Y, TY); }
        }
        M2 MX, MY;
        MX.a11 = __shfl(X.a11, Q, 64); MX.a12 = __shfl(X.a12, Q, 64);
        MX.a21 = __shfl(X.a21, Q, 64); MX.a22 = __shfl(X.a22, Q, 64);
        MY.a11 = __shfl(Y.a11, Q, 64); MY.a12 = __shfl(Y.a12, Q, 64);
        MY.a21 = __shfl(Y.a21, Q, 64); MY.a22 = __shfl(Y.a22, Q, 64);
        ldrift(MX, 0.45); ldrift(MY, 0.45);

        double con[20];
        #pragma unroll
        for (int v = 0; v < 20; ++v) con[v] = 0.0;
        if (lane <= Q) {
            double Lj = (lane == 0 || lane == Q) ? 0.45 : 0.9;
            double a = X.a21, b = X.a22, c2 = Y.a21, d2 = Y.a22;
            double Rx = MX.a11*b - MX.a12*a;
            double Ry = MY.a11*d2 - MY.a12*c2;
            double g = 0.5 * Lj * Rx;
            double h = 0.5 * Lj * Ry;
            con[0]=g*a*a*a;   con[1]=3.0*g*a*a*b;  con[2]=3.0*g*a*b*b;  con[3]=g*b*b*b;
            con[4]=g*a*c2*c2; con[5]=2.0*g*a*c2*d2; con[6]=g*a*d2*d2;
            con[7]=g*b*c2*c2; con[8]=2.0*g*b*c2*d2; con[9]=g*b*d2*d2;
            con[10]=h*c2*c2*c2; con[11]=3.0*h*c2*c2*d2; con[12]=3.0*h*c2*d2*d2; con[13]=h*d2*d2*d2;
            con[14]=h*c2*a*a;  con[15]=2.0*h*c2*a*b; con[16]=h*c2*b*b;
            con[17]=h*d2*a*a;  con[18]=2.0*h*d2*a*b; con[19]=h*d2*b*b;
        }
        #pragma unroll
        for (int v = 0; v < 20; ++v) {
            #pragma unroll
            for (int off = 32; off > 0; off >>= 1)
                con[v] += __shfl_down(con[v], off, 64);
        }
        if (lane == 0) {
            #pragma unroll
            for (int v = 0; v < 10; ++v) { cfs[16+v]=(float)con[v]; cfs[26+v]=(float)con[10+v]; }
        }
    }
    __syncthreads();   // Mn + cubic cfs ready

    // ---- Phase C: Newton fit on 4 nodes, threads 0-3 (registers only) ----
    if (tid < 4) {
        constexpr double TN[NNODE] = {U0, U1, U2, U3};
        double d[NNODE];
        #pragma unroll
        for (int m = 0; m < NNODE; ++m) d[m] = Mn[m][tid];
        #pragma unroll
        for (int k = 1; k < NNODE; ++k) {
            #pragma unroll
            for (int m = NNODE - 1; m >= 1; --m) {
                if (m >= k) d[m] = (d[m] - d[m-1]) * (1.0 / (TN[m] - TN[m-k]));
            }
        }
        double c[NNODE];
        c[0] = d[NNODE-1];
        #pragma unroll
        for (int k = 1; k < NNODE; ++k) c[k] = 0.0;
        #pragma unroll
        for (int m = NNODE - 2; m >= 0; --m) {
            #pragma unroll
            for (int k = NNODE - 1; k >= 1; --k) c[k] = c[k-1] - TN[m]*c[k];
            c[0] = d[m] - TN[m]*c[0];
        }
        #pragma unroll
        for (int k = 0; k < NNODE; ++k) cfs[tid*4 + k] = (float)c[k];
    }
    __syncthreads();   // all 36 coeffs ready

    // broadcast coefficients into SGPRs
    float h[16], Cx[10], Cy[10];
    #pragma unroll
    for (int k = 0; k < 16; ++k) h[k] = uniflds(cfs + k);
    #pragma unroll
    for (int k = 0; k < 10; ++k) { Cx[k] = uniflds(cfs + 16 + k); Cy[k] = uniflds(cfs + 26 + k); }

    const float inva = (float)(1.0 / PZ_A);
    float s1x = 0.f, s2x = 0.f, s1y = 0.f, s2y = 0.f;

    auto track = [&](float x, float p, float y, float q, float pz) {
        float t = pz * inva;
        float m11 = h[3], m12 = h[7], n11 = h[11], n12 = h[15];
        #pragma unroll
        for (int k = 2; k >= 0; --k) {
            m11 = fmaf(m11, t, h[k]);
            m12 = fmaf(m12, t, h[4+k]);
            n11 = fmaf(n11, t, h[8+k]);
            n12 = fmaf(n12, t, h[12+k]);
        }
        float xx = x*x, xp = x*p, pp = p*p;
        float yy = y*y, yq = y*q, qq = q*q;
        float A1 = Cx[0]*xx; A1=fmaf(Cx[1],xp,A1); A1=fmaf(Cx[2],pp,A1);
        A1=fmaf(Cx[4],yy,A1); A1=fmaf(Cx[5],yq,A1); A1=fmaf(Cx[6],qq,A1);
        float A2 = Cx[3]*pp; A2=fmaf(Cx[7],yy,A2); A2=fmaf(Cx[8],yq,A2); A2=fmaf(Cx[9],qq,A2);
        float B1 = Cy[0]*yy; B1=fmaf(Cy[1],yq,B1); B1=fmaf(Cy[2],qq,B1);
        B1=fmaf(Cy[4],xx,B1); B1=fmaf(Cy[5],xp,B1); B1=fmaf(Cy[6],pp,B1);
        float B2 = Cy[3]*qq; B2=fmaf(Cy[7],xx,B2); B2=fmaf(Cy[8],xp,B2); B2=fmaf(Cy[9],pp,B2);
        float xf = fmaf(m11, x, m12*p); xf = fmaf(x, A1, xf); xf = fmaf(p, A2, xf);
        float yf = fmaf(n11, y, n12*q); yf = fmaf(y, B1, yf); yf = fmaf(q, B2, yf);
        s1x += xf; s2x = fmaf(xf, xf, s2x);
        s1y += yf; s2y = fmaf(yf, yf, s2y);
    };

    const int gstride = gridDim.x * blockDim.x;
    for (int i = blockIdx.x * blockDim.x + tid; i < n4; i += gstride) {
        float4 xv  = ((const float4*)xs)[i];
        float4 pxv = ((const float4*)pxs)[i];
        float4 yv  = ((const float4*)ys)[i];
        float4 pyv = ((const float4*)pys)[i];
        float4 pzv = ((const float4*)pzs)[i];
        track(xv.x, pxv.x, yv.x, pyv.x, pzv.x);
        track(xv.y, pxv.y, yv.y, pyv.y, pzv.y);
        track(xv.z, pxv.z, yv.z, pyv.z, pzv.z);
        track(xv.w, pxv.w, yv.w, pyv.w, pzv.w);
    }
    if (blockIdx.x == 0 && tid == 0) {
        for (int r = 0; r < ntail; ++r) {
            int idx = 4*n4 + r;
            track(xs[idx], pxs[idx], ys[idx], pys[idx], pzs[idx]);
        }
    }

    // wave shuffle reduce, then LDS across 4 waves
    for (int off = 32; off > 0; off >>= 1) {
        s1x += __shfl_down(s1x, off, 64);
        s2x += __shfl_down(s2x, off, 64);
        s1y += __shfl_down(s1y, off, 64);
        s2y += __shfl_down(s2y, off, 64);
    }
    __shared__ float red[4][4];
    if (lane == 0) {
        red[wid][0] = s1x; red[wid][1] = s2x;
        red[wid][2] = s1y; red[wid][3] = s2y;
    }
    __syncthreads();
    if (tid == 0) {
        float a = 0.f, b = 0.f, c = 0.f, d = 0.f;
        const int nw = (blockDim.x + 63) >> 6;
        for (int w = 0; w < nw; ++w) {
            a += red[w][0]; b += red[w][1];
            c += red[w][2]; d += red[w][3];
        }
        partials[blockIdx.x] = make_float4(a, b, c, d);  // no atomics
    }
}

__global__ __launch_bounds__(256) void finalize_kernel(
    const float4* __restrict__ partials, int nparts,
    float* __restrict__ out, int N)
{
    double a = 0.0, b = 0.0, c = 0.0, d = 0.0;
    for (int i = threadIdx.x; i < nparts; i += 256) {
        float4 p = partials[i];
        a += (double)p.x; b += (double)p.y;
        c += (double)p.z; d += (double)p.w;
    }
    for (int off = 32; off > 0; off >>= 1) {
        a += __shfl_down(a, off, 64);
        b += __shfl_down(b, off, 64);
        c += __shfl_down(c, off, 64);
        d += __shfl_down(d, off, 64);
    }
    __shared__ double red[4][4];
    const int lane = threadIdx.x & 63;
    const int wid  = threadIdx.x >> 6;
    if (lane == 0) {
        red[wid][0] = a; red[wid][1] = b; red[wid][2] = c; red[wid][3] = d;
    }
    __syncthreads();
    if (threadIdx.x == 0) {
        double sa = 0, sb = 0, sc = 0, sd = 0;
        for (int w = 0; w < 4; ++w) {
            sa += red[w][0]; sb += red[w][1];
            sc += red[w][2]; sd += red[w][3];
        }
        const double n  = (double)N;
        const double vx = (sb - sa*sa/n) / (n - 1.0);
        const double vy = (sd - sc*sc/n) / (n - 1.0);
        const double dx = sqrt(vx) - SIGMA_T;
        const double dy = sqrt(vy) - SIGMA_T;
        out[0] = (float)sqrt(dx*dx + dy*dy);
    }
}

extern "C" void kernel_launch(void* const* d_in, const int* in_sizes, int n_in,
                              void* d_out, int out_size, void* d_ws, size_t ws_size,
                              hipStream_t stream) {
    const float* xs  = (const float*)d_in[0];
    const float* pxs = (const float*)d_in[1];
    const float* ys  = (const float*)d_in[2];
    const float* pys = (const float*)d_in[3];
    // d_in[4] = z : dead
    const float* pzs = (const float*)d_in[5];
    const float* ks  = (const float*)d_in[6];
    // d_in[7] = n_slices : dead (exact slice composition)

    const int N = in_sizes[0];
    const int Q = in_sizes[6];

    float4* partials = (float4*)((char*)d_ws + 4096);

    const int n4 = N >> 2;
    const int ntail = N & 3;
    int blocks = (n4 + 255) / 256;      // 4 particles/thread (R8's beam config)
    if (blocks < 1) blocks = 1;
    if (blocks > MAXBLK) blocks = MAXBLK;
    beam_fused_kernel<<<blocks, 256, 0, stream>>>(
        xs, pxs, ys, pys, pzs, ks, Q, n4, ntail, partials);
    finalize_kernel<<<1, 256, 0, stream>>>(partials, blocks, (float*)d_out, N);
}

// Round 11
// 18.456 us; speedup vs baseline: 1.4957x; 1.4957x over previous
//
#include <hip/hip_runtime.h>
#include <math.h>

// Beamline: D(0.45) [Q_c D(0.9)]x19 Q_19 D(0.45). Output = hypot(std(x)-s, std(y)-s).
// Only final x,y matter -> final px,py, z-channel, n_slices all dead.
//   x_f = m11(pz)*x0 + m12(pz)*px0  (chromatic linear map, deg-3 Chebyshev in pz)
//       + cubic(x0,px0,y0,py0)      (first-order drift-nonlinearity kicks, pz=0)
// Round-11: 2-node fusion with ALL-F32 prep. Rationale: coefficients are
// consumed in f32 anyway; f32 prep error ~1e-6 relative -> output error ~1e-7
// (threshold 9.9e-4). f32 halves prep registers (con[20]: 40->20 VGPR) and
// doubles slot rate, fixing R9's occupancy collision (pre-issued loads held
// across heavy f64 prep) and R10's idle-memory prep (no pre-issue, 2x blocks).
// Structure: pre-issue first particle batch -> prep (waves 0-1: 4 Chebyshev
// node lattices via 32-cell tree product; wave 2: cubic via prefix scan;
// concurrent) -> Newton fit -> track 8 particles/thread, 977 blocks.
// Lessons kept: no contended atomics (R2), no dynamic-index arrays (R3),
// no per-block device-scope fences (R6).

#define SIGMA_T 0.005
#define PZ_A 6.5e-3f
#define NNODE 4
#define MAXQ 32
#define MAXBLK 2048

// cos(pi*(2i+1)/8), i = 0..3
#define U0  0.92387953f
#define U1  0.38268343f
#define U2 (-0.38268343f)
#define U3 (-0.92387953f)

struct M2f { float a11, a12, a21, a22; };

// quad 2x2 via signed-u series (f32): u = A*L^2; |u|<=0.05 -> trunc err ~1e-10
__device__ inline M2f quadmatF(float A, float rp, float irp, float L) {
    float u = A * L * L;
    float C = fmaf(u, fmaf(u, fmaf(u, 1.0f/720.0f, 1.0f/24.0f), 0.5f), 1.0f);
    float S = fmaf(u, fmaf(u, fmaf(u, 1.0f/5040.0f, 1.0f/120.0f), 1.0f/6.0f), 1.0f);
    M2f m;
    float LS = L * S;
    m.a11 = C;
    m.a12 = LS * irp;
    m.a21 = A * LS * rp;
    m.a22 = C;
    return m;
}
__device__ inline void lmulF(M2f& M, const M2f& E) {  // M <- E*M
    float n11 = fmaf(E.a11, M.a11, E.a12*M.a21);
    float n12 = fmaf(E.a11, M.a12, E.a12*M.a22);
    float n21 = fmaf(E.a21, M.a11, E.a22*M.a21);
    float n22 = fmaf(E.a21, M.a12, E.a22*M.a22);
    M.a11=n11; M.a12=n12; M.a21=n21; M.a22=n22;
}
__device__ inline void ldriftF(M2f& M, float d) {   // M <- [[1,d],[0,1]]*M
    M.a11 = fmaf(d, M.a21, M.a11);
    M.a12 = fmaf(d, M.a22, M.a12);
}
__device__ inline M2f mmulF(const M2f& A, const M2f& B) {  // A*B
    M2f r;
    r.a11 = fmaf(A.a11, B.a11, A.a12*B.a21);
    r.a12 = fmaf(A.a11, B.a12, A.a12*B.a22);
    r.a21 = fmaf(A.a21, B.a11, A.a22*B.a21);
    r.a22 = fmaf(A.a21, B.a12, A.a22*B.a22);
    return r;
}
__device__ inline M2f shfl_down_m2f(const M2f& m, int d, int w) {
    M2f r;
    r.a11 = __shfl_down(m.a11, d, w);
    r.a12 = __shfl_down(m.a12, d, w);
    r.a21 = __shfl_down(m.a21, d, w);
    r.a22 = __shfl_down(m.a22, d, w);
    return r;
}
__device__ inline M2f shfl_up_m2f(const M2f& m, int d, int w) {
    M2f r;
    r.a11 = __shfl_up(m.a11, d, w);
    r.a12 = __shfl_up(m.a12, d, w);
    r.a21 = __shfl_up(m.a21, d, w);
    r.a22 = __shfl_up(m.a22, d, w);
    return r;
}

__device__ inline float uniflds(const float* p) {
    return __int_as_float(__builtin_amdgcn_readfirstlane(__float_as_int(*p)));
}

// cfs layout (LDS):
//  [0..15]  horner: f*4+k, f in {mx11,mx12,my11,my12}, ascending power of t=pz/PZ_A
//  [16..25] Cx[10]: dx = x(C0 xx+C1 xp+C2 pp+C4 yy+C5 yq+C6 qq) + p(C3 pp+C7 yy+C8 yq+C9 qq)
//  [26..35] Cy[10]: symmetric
__global__ __launch_bounds__(256, 4) void beam_fused_kernel(
    const float* __restrict__ xs, const float* __restrict__ pxs,
    const float* __restrict__ ys, const float* __restrict__ pys,
    const float* __restrict__ pzs, const float* __restrict__ ks,
    int Q, int n4, int ntail, float4* __restrict__ partials)
{
    __shared__ float Mn[NNODE][4];
    __shared__ float cfs[36];
    __shared__ float klds[MAXQ];

    const int tid  = threadIdx.x;
    const int lane = tid & 63;
    const int wid  = tid >> 6;
    if (Q > MAXQ) Q = MAXQ;

    if (tid < MAXQ) klds[tid] = (tid < Q) ? ks[tid] : 0.0f;

    // pre-issue first particle batch: 20 VGPR held, hides HBM latency under
    // prep (f32 prep is register-light enough that this fits 4 blocks/CU)
    const int i0 = blockIdx.x * blockDim.x + tid;
    const bool have0 = (i0 < n4);
    float4 xv{}, pxv{}, yv{}, pyv{}, pzv{};
    if (have0) {
        xv  = ((const float4*)xs)[i0];
        pxv = ((const float4*)pxs)[i0];
        yv  = ((const float4*)ys)[i0];
        pyv = ((const float4*)pys)[i0];
        pzv = ((const float4*)pzs)[i0];
    }
    __syncthreads();   // klds visible

    if (tid < 128) {
        // ---- Phase A (waves 0-1): 4 Chebyshev nodes x 32 cells, ordered
        //      5-step shuffle tree product (structure verified R8/R10) ----
        const int cell = tid & 31;
        const int node = tid >> 5;
        const float TNv[NNODE] = {U0, U1, U2, U3};
        float t = TNv[node];             // uniform within 32-group
        float pz = PZ_A * t;
        float rp = 1.0f + pz;
        float irp = 1.0f / rp;
        M2f X{1,0,0,1}, Y{1,0,0,1};
        if (cell < Q) {
            if (cell == 0) { ldriftF(X, 0.45f*irp); ldriftF(Y, 0.45f*irp); }
            float k1n = klds[cell] * irp;
            lmulF(X, quadmatF(-k1n, rp, irp, 0.1f));
            lmulF(Y, quadmatF( k1n, rp, irp, 0.1f));
            float d = ((cell == Q-1) ? 0.45f : 0.9f) * irp;
            ldriftF(X, d); ldriftF(Y, d);
        }
        #pragma unroll
        for (int s = 0; s < 5; ++s) {
            M2f TX = shfl_down_m2f(X, 1 << s, 32);
            M2f TY = shfl_down_m2f(Y, 1 << s, 32);
            X = mmulF(TX, X);
            Y = mmulF(TY, Y);
        }
        if (cell == 0) {
            Mn[node][0]=X.a11; Mn[node][1]=X.a12; Mn[node][2]=Y.a11; Mn[node][3]=Y.a12;
        }
    } else if (wid == 2) {
        // ---- Phase B (wave 2, concurrent with A): cubic drift-kick coeffs at
        //      pz=0 via Hillis-Steele prefix matrix scan over drifts ----
        M2f X{1,0,0,1}, Y{1,0,0,1};
        if (lane >= 1 && lane <= Q) {
            float Lprev = (lane == 1) ? 0.45f : 0.9f;
            ldriftF(X, Lprev); ldriftF(Y, Lprev);
            float k1 = klds[lane-1];
            lmulF(X, quadmatF(-k1, 1.0f, 1.0f, 0.1f));
            lmulF(Y, quadmatF( k1, 1.0f, 1.0f, 0.1f));
        }
        #pragma unroll
        for (int s = 0; s < 5; ++s) {
            M2f TX = shfl_up_m2f(X, 1 << s, 64);
            M2f TY = shfl_up_m2f(Y, 1 << s, 64);
            if (lane >= (1 << s)) { X = mmulF(X, TX); Y = mmulF(Y, TY); }
        }
        M2f MX, MY;
        MX.a11 = __shfl(X.a11, Q, 64); MX.a12 = __shfl(X.a12, Q, 64);
        MX.a21 = __shfl(X.a21, Q, 64); MX.a22 = __shfl(X.a22, Q, 64);
        MY.a11 = __shfl(Y.a11, Q, 64); MY.a12 = __shfl(Y.a12, Q, 64);
        MY.a21 = __shfl(Y.a21, Q, 64); MY.a22 = __shfl(Y.a22, Q, 64);
        ldriftF(MX, 0.45f); ldriftF(MY, 0.45f);

        float con[20];
        #pragma unroll
        for (int v = 0; v < 20; ++v) con[v] = 0.0f;
        if (lane <= Q) {
            float Lj = (lane == 0 || lane == Q) ? 0.45f : 0.9f;
            float a = X.a21, b = X.a22, c2 = Y.a21, d2 = Y.a22;
            float Rx = MX.a11*b - MX.a12*a;
            float Ry = MY.a11*d2 - MY.a12*c2;
            float g = 0.5f * Lj * Rx;
            float h = 0.5f * Lj * Ry;
            con[0]=g*a*a*a;   con[1]=3.0f*g*a*a*b;  con[2]=3.0f*g*a*b*b;  con[3]=g*b*b*b;
            con[4]=g*a*c2*c2; con[5]=2.0f*g*a*c2*d2; con[6]=g*a*d2*d2;
            con[7]=g*b*c2*c2; con[8]=2.0f*g*b*c2*d2; con[9]=g*b*d2*d2;
            con[10]=h*c2*c2*c2; con[11]=3.0f*h*c2*c2*d2; con[12]=3.0f*h*c2*d2*d2; con[13]=h*d2*d2*d2;
            con[14]=h*c2*a*a;  con[15]=2.0f*h*c2*a*b; con[16]=h*c2*b*b;
            con[17]=h*d2*a*a;  con[18]=2.0f*h*d2*a*b; con[19]=h*d2*b*b;
        }
        #pragma unroll
        for (int v = 0; v < 20; ++v) {
            #pragma unroll
            for (int off = 32; off > 0; off >>= 1)
                con[v] += __shfl_down(con[v], off, 64);
        }
        if (lane == 0) {
            #pragma unroll
            for (int v = 0; v < 10; ++v) { cfs[16+v]=con[v]; cfs[26+v]=con[10+v]; }
        }
    }
    __syncthreads();   // Mn + cubic cfs ready

    // ---- Phase C: Newton fit on 4 nodes, threads 0-3 (f32, registers) ----
    if (tid < 4) {
        constexpr float TN[NNODE] = {U0, U1, U2, U3};
        float d[NNODE];
        #pragma unroll
        for (int m = 0; m < NNODE; ++m) d[m] = Mn[m][tid];
        #pragma unroll
        for (int k = 1; k < NNODE; ++k) {
            #pragma unroll
            for (int m = NNODE - 1; m >= 1; --m) {
                if (m >= k) d[m] = (d[m] - d[m-1]) * (1.0f / (TN[m] - TN[m-k]));
            }
        }
        float c[NNODE];
        c[0] = d[NNODE-1];
        #pragma unroll
        for (int k = 1; k < NNODE; ++k) c[k] = 0.0f;
        #pragma unroll
        for (int m = NNODE - 2; m >= 0; --m) {
            #pragma unroll
            for (int k = NNODE - 1; k >= 1; --k) c[k] = c[k-1] - TN[m]*c[k];
            c[0] = d[m] - TN[m]*c[0];
        }
        #pragma unroll
        for (int k = 0; k < NNODE; ++k) cfs[tid*4 + k] = c[k];
    }
    __syncthreads();   // all 36 coeffs ready

    // broadcast coefficients into SGPRs
    float h[16], Cx[10], Cy[10];
    #pragma unroll
    for (int k = 0; k < 16; ++k) h[k] = uniflds(cfs + k);
    #pragma unroll
    for (int k = 0; k < 10; ++k) { Cx[k] = uniflds(cfs + 16 + k); Cy[k] = uniflds(cfs + 26 + k); }

    const float inva = 1.0f / PZ_A;
    float s1x = 0.f, s2x = 0.f, s1y = 0.f, s2y = 0.f;

    auto track = [&](float x, float p, float y, float q, float pz) {
        float t = pz * inva;
        float m11 = h[3], m12 = h[7], n11 = h[11], n12 = h[15];
        #pragma unroll
        for (int k = 2; k >= 0; --k) {
            m11 = fmaf(m11, t, h[k]);
            m12 = fmaf(m12, t, h[4+k]);
            n11 = fmaf(n11, t, h[8+k]);
            n12 = fmaf(n12, t, h[12+k]);
        }
        float xx = x*x, xp = x*p, pp = p*p;
        float yy = y*y, yq = y*q, qq = q*q;
        float A1 = Cx[0]*xx; A1=fmaf(Cx[1],xp,A1); A1=fmaf(Cx[2],pp,A1);
        A1=fmaf(Cx[4],yy,A1); A1=fmaf(Cx[5],yq,A1); A1=fmaf(Cx[6],qq,A1);
        float A2 = Cx[3]*pp; A2=fmaf(Cx[7],yy,A2); A2=fmaf(Cx[8],yq,A2); A2=fmaf(Cx[9],qq,A2);
        float B1 = Cy[0]*yy; B1=fmaf(Cy[1],yq,B1); B1=fmaf(Cy[2],qq,B1);
        B1=fmaf(Cy[4],xx,B1); B1=fmaf(Cy[5],xp,B1); B1=fmaf(Cy[6],pp,B1);
        float B2 = Cy[3]*qq; B2=fmaf(Cy[7],xx,B2); B2=fmaf(Cy[8],xp,B2); B2=fmaf(Cy[9],pp,B2);
        float xf = fmaf(m11, x, m12*p); xf = fmaf(x, A1, xf); xf = fmaf(p, A2, xf);
        float yf = fmaf(n11, y, n12*q); yf = fmaf(y, B1, yf); yf = fmaf(q, B2, yf);
        s1x += xf; s2x = fmaf(xf, xf, s2x);
        s1y += yf; s2y = fmaf(yf, yf, s2y);
    };

    if (have0) {
        track(xv.x, pxv.x, yv.x, pyv.x, pzv.x);
        track(xv.y, pxv.y, yv.y, pyv.y, pzv.y);
        track(xv.z, pxv.z, yv.z, pyv.z, pzv.z);
        track(xv.w, pxv.w, yv.w, pyv.w, pzv.w);
    }
    const int gstride = gridDim.x * blockDim.x;
    for (int i = i0 + gstride; i < n4; i += gstride) {
        float4 xw  = ((const float4*)xs)[i];
        float4 pxw = ((const float4*)pxs)[i];
        float4 yw  = ((const float4*)ys)[i];
        float4 pyw = ((const float4*)pys)[i];
        float4 pzw = ((const float4*)pzs)[i];
        track(xw.x, pxw.x, yw.x, pyw.x, pzw.x);
        track(xw.y, pxw.y, yw.y, pyw.y, pzw.y);
        track(xw.z, pxw.z, yw.z, pyw.z, pzw.z);
        track(xw.w, pxw.w, yw.w, pyw.w, pzw.w);
    }
    if (blockIdx.x == 0 && tid == 0) {
        for (int r = 0; r < ntail; ++r) {
            int idx = 4*n4 + r;
            track(xs[idx], pxs[idx], ys[idx], pys[idx], pzs[idx]);
        }
    }

    // wave shuffle reduce, then LDS across 4 waves
    for (int off = 32; off > 0; off >>= 1) {
        s1x += __shfl_down(s1x, off, 64);
        s2x += __shfl_down(s2x, off, 64);
        s1y += __shfl_down(s1y, off, 64);
        s2y += __shfl_down(s2y, off, 64);
    }
    __shared__ float red[4][4];
    if (lane == 0) {
        red[wid][0] = s1x; red[wid][1] = s2x;
        red[wid][2] = s1y; red[wid][3] = s2y;
    }
    __syncthreads();
    if (tid == 0) {
        float a = 0.f, b = 0.f, c = 0.f, d = 0.f;
        const int nw = (blockDim.x + 63) >> 6;
        for (int w = 0; w < nw; ++w) {
            a += red[w][0]; b += red[w][1];
            c += red[w][2]; d += red[w][3];
        }
        partials[blockIdx.x] = make_float4(a, b, c, d);  // no atomics
    }
}

__global__ __launch_bounds__(256) void finalize_kernel(
    const float4* __restrict__ partials, int nparts,
    float* __restrict__ out, int N)
{
    double a = 0.0, b = 0.0, c = 0.0, d = 0.0;
    for (int i = threadIdx.x; i < nparts; i += 256) {
        float4 p = partials[i];
        a += (double)p.x; b += (double)p.y;
        c += (double)p.z; d += (double)p.w;
    }
    for (int off = 32; off > 0; off >>= 1) {
        a += __shfl_down(a, off, 64);
        b += __shfl_down(b, off, 64);
        c += __shfl_down(c, off, 64);
        d += __shfl_down(d, off, 64);
    }
    __shared__ double red[4][4];
    const int lane = threadIdx.x & 63;
    const int wid  = threadIdx.x >> 6;
    if (lane == 0) {
        red[wid][0] = a; red[wid][1] = b; red[wid][2] = c; red[wid][3] = d;
    }
    __syncthreads();
    if (threadIdx.x == 0) {
        double sa = 0, sb = 0, sc = 0, sd = 0;
        for (int w = 0; w < 4; ++w) {
            sa += red[w][0]; sb += red[w][1];
            sc += red[w][2]; sd += red[w][3];
        }
        const double n  = (double)N;
        const double vx = (sb - sa*sa/n) / (n - 1.0);
        const double vy = (sd - sc*sc/n) / (n - 1.0);
        const double dx = sqrt(vx) - SIGMA_T;
        const double dy = sqrt(vy) - SIGMA_T;
        out[0] = (float)sqrt(dx*dx + dy*dy);
    }
}

extern "C" void kernel_launch(void* const* d_in, const int* in_sizes, int n_in,
                              void* d_out, int out_size, void* d_ws, size_t ws_size,
                              hipStream_t stream) {
    const float* xs  = (const float*)d_in[0];
    const float* pxs = (const float*)d_in[1];
    const float* ys  = (const float*)d_in[2];
    const float* pys = (const float*)d_in[3];
    // d_in[4] = z : dead
    const float* pzs = (const float*)d_in[5];
    const float* ks  = (const float*)d_in[6];
    // d_in[7] = n_slices : dead (exact slice composition)

    const int N = in_sizes[0];
    const int Q = in_sizes[6];

    float4* partials = (float4*)((char*)d_ws + 4096);

    const int n4 = N >> 2;
    const int ntail = N & 3;
    int blocks = (n4 + 511) / 512;      // 8 particles/thread -> 977 blocks
    if (blocks < 1) blocks = 1;
    if (blocks > MAXBLK) blocks = MAXBLK;
    beam_fused_kernel<<<blocks, 256, 0, stream>>>(
        xs, pxs, ys, pys, pzs, ks, Q, n4, ntail, partials);
    finalize_kernel<<<1, 256, 0, stream>>>(partials, blocks, (float*)d_out, N);
}